// Round 3
// baseline (612.923 us; speedup 1.0000x reference)
//
#include <hip/hip_runtime.h>

#define NEGF -1e30f
#define EPSF 1e-5f

typedef __attribute__((ext_vector_type(8))) short bf16x8;
typedef __attribute__((ext_vector_type(4))) float f32x4;

// ws layout, ushort units
#define WSU_PW 0            // 4 x 128x128 bf16, natural [o][c]
#define WSU_FC 65536        // [o][c]
#define WSU_WO 81920        // [f][j]
#define WSU_WQ 98304        // [j][l]
#define WSU_WK 114688
#define WSU_WV 131072
#define WSU_END 147456      // then PE as float[16384]

__device__ __forceinline__ unsigned short f2bf(float x) {
  unsigned int u = __float_as_uint(x);
  u += 0x7fffu + ((u >> 16) & 1u);
  return (unsigned short)(u >> 16);
}
__device__ __forceinline__ float bf2f(unsigned short u) {
  return __uint_as_float(((unsigned int)u) << 16);
}
__device__ __forceinline__ f32x4 mfma16(bf16x8 a, bf16x8 b, f32x4 c) {
  return __builtin_amdgcn_mfma_f32_16x16x32_bf16(a, b, c, 0, 0, 0);
}

__global__ __launch_bounds__(128) void prep_kernel(
    const float* __restrict__ pw_w, const float* __restrict__ fc_w,
    const float* __restrict__ Wo, const float* __restrict__ Wq,
    const float* __restrict__ Wk, const float* __restrict__ Wv,
    unsigned short* __restrict__ wsu) {
  int job = blockIdx.x, r = blockIdx.y, c = threadIdx.x;
  int idx = r * 128 + c;
  if (job < 4)       wsu[WSU_PW + job * 16384 + idx] = f2bf(pw_w[job * 16384 + idx]);
  else if (job == 4) wsu[WSU_FC + idx] = f2bf(fc_w[idx]);
  else if (job == 5) wsu[WSU_WO + idx] = f2bf(Wo[idx]);
  else if (job == 6) wsu[WSU_WQ + idx] = f2bf(Wq[idx]);
  else if (job == 7) wsu[WSU_WK + idx] = f2bf(Wk[idx]);
  else if (job == 8) wsu[WSU_WV + idx] = f2bf(Wv[idx]);
  else {
    float* pe = (float*)(wsu + WSU_END);
    int d = r, pos = c;
    double freq, phase;
    if ((d & 1) == 0) { freq = pow(10000.0, -(double)d / 128.0); phase = 0.0; }
    else { freq = -pow(10000.0, (1.0 - (double)d) / 128.0); phase = 1.5707963267948966; }
    pe[d * 128 + pos] = (float)sin((double)pos * freq + phase);
  }
}

// plane LN stats over 512 threads x 32 regs
__device__ __forceinline__ void ln_stats(const float* resv, float* red, int t,
                                         float& mu, float& inv) {
  float s = 0.f, s2 = 0.f;
#pragma unroll
  for (int i = 0; i < 32; i++) { float v = resv[i]; s += v; s2 += v * v; }
#pragma unroll
  for (int off = 32; off > 0; off >>= 1) {
    s += __shfl_down(s, off, 64);
    s2 += __shfl_down(s2, off, 64);
  }
  if ((t & 63) == 0) { red[(t >> 6) * 2] = s; red[(t >> 6) * 2 + 1] = s2; }
  __syncthreads();
  float S = 0.f, S2 = 0.f;
#pragma unroll
  for (int i = 0; i < 8; i++) { S += red[2 * i]; S2 += red[2 * i + 1]; }
  mu = S * (1.0f / 16384.0f);
  float var = S2 * (1.0f / 16384.0f) - mu * mu;
  inv = rsqrtf(var + EPSF);
}

__global__ __launch_bounds__(512, 1) void enc_kernel(
    const float* __restrict__ x, const int* __restrict__ mask,
    const float* __restrict__ dw_w, const float* __restrict__ dw_b,
    const float* __restrict__ pw_b,
    const float* __restrict__ normb_w, const float* __restrict__ normb_b,
    const float* __restrict__ norms_w, const float* __restrict__ norms_b,
    const float* __restrict__ norme_w, const float* __restrict__ norme_b,
    const float* __restrict__ bq, const float* __restrict__ bk,
    const float* __restrict__ bv, const float* __restrict__ bo,
    const float* __restrict__ fc_b, const unsigned short* __restrict__ wsu,
    const float* __restrict__ pe, float* __restrict__ out) {
  __shared__ __align__(16) float S[128 * 130];            // fp32 matmul-out scratch (+ MHA union)
  __shared__ __align__(16) unsigned short Xn_raw[128 * 136 + 16];
  __shared__ __align__(16) unsigned short HT[128 * 136];  // h^T / ATT / X^T
  __shared__ float mask_s[128];
  __shared__ float red[16];
  unsigned short* Xn = Xn_raw + 8;
  // MHA union inside S (64,000 shorts <= 66,560 floats*2)
  unsigned short* Pn  = (unsigned short*)S;   // 128*136
  unsigned short* Qh  = Pn + 128 * 136;       // 128*40
  unsigned short* Kh  = Qh + 128 * 40;        // 128*40
  unsigned short* VTh = Kh + 128 * 40;        // 32*136

  const int t = threadIdx.x;
  const int b = blockIdx.x;
  const int lane = t & 63;
  const int r16 = lane & 15;
  const int quad = lane >> 4;
  const int m0 = __builtin_amdgcn_readfirstlane((t >> 6) << 4);   // wave m-tile base
  const int l = t & 127;                                          // owned column
  const int obase = __builtin_amdgcn_readfirstlane((t >> 7) << 5);
  const int dw_o = t & 127;                                       // depthwise row
  const int dw_seg = __builtin_amdgcn_readfirstlane(t >> 7);      // depthwise l-segment

  if (t < 128) mask_s[t] = (float)mask[b * 128 + t];

  float res[32];
  {
    const float* xb = x + (size_t)b * 16384;
#pragma unroll
    for (int i = 0; i < 32; i++) {
      int o = obase + i;
      res[i] = xb[o * 128 + l] + pe[o * 128 + l];
    }
  }
  {
    float mu, inv;
    ln_stats(res, red, t, mu, inv);
#pragma unroll
    for (int i = 0; i < 32; i++) {
      int o = obase + i;
      Xn[o * 136 + l] = f2bf((res[i] - mu) * inv * normb_w[o * 128 + l] + normb_b[o * 128 + l]);
    }
    __syncthreads();
  }

  // ================= 4x separable conv blocks =================
#pragma unroll 1
  for (int layer = 0; layer < 4; layer++) {
    // depthwise conv7: Xn -> HT (transposed h^T[l][c])
    {
      const float* dwp = dw_w + layer * 896 + dw_o * 7;
      float wreg[7];
#pragma unroll
      for (int j = 0; j < 7; j++) wreg[j] = dwp[j];
      float bias = dw_b[layer * 128 + dw_o];
      const unsigned short* xrow = Xn + dw_o * 136 + dw_seg * 32 - 8;
      float f[48];
#pragma unroll
      for (int i6 = 0; i6 < 6; i6++) {
        bf16x8 v = *(const bf16x8*)(xrow + 8 * i6);
#pragma unroll
        for (int j = 0; j < 8; j++) f[i6 * 8 + j] = bf2f((unsigned short)v[j]);
      }
      if (dw_seg == 0) {
#pragma unroll
        for (int i = 0; i < 8; i++) f[i] = 0.f;
      }
      if (dw_seg == 3) {
#pragma unroll
        for (int i = 40; i < 48; i++) f[i] = 0.f;
      }
      float accv[32];
#pragma unroll
      for (int c = 0; c < 32; c++) {
        float a = bias;
#pragma unroll
        for (int j = 0; j < 7; j++) a += f[c + 5 + j] * wreg[j];  // idx = c + j + 5
        accv[c] = a;
      }
#pragma unroll
      for (int c = 0; c < 32; c++) HT[(dw_seg * 32 + c) * 136 + dw_o] = f2bf(accv[c]);
    }
    __syncthreads();
    // pointwise: D[o][l] = sum_c pw[o][c] * hT[l][c]
    {
      const unsigned short* pwp = wsu + WSU_PW + (layer << 14) + (m0 + r16) * 128 + quad * 8;
      bf16x8 a0 = *(const bf16x8*)(pwp);
      bf16x8 a1 = *(const bf16x8*)(pwp + 32);
      bf16x8 a2 = *(const bf16x8*)(pwp + 64);
      bf16x8 a3 = *(const bf16x8*)(pwp + 96);
#pragma unroll
      for (int n = 0; n < 8; n++) {
        const unsigned short* hb = HT + (16 * n + r16) * 136 + quad * 8;
        f32x4 c = {0.f, 0.f, 0.f, 0.f};
        c = mfma16(a0, *(const bf16x8*)(hb), c);
        c = mfma16(a1, *(const bf16x8*)(hb + 32), c);
        c = mfma16(a2, *(const bf16x8*)(hb + 64), c);
        c = mfma16(a3, *(const bf16x8*)(hb + 96), c);
        float* sp = S + (m0 + quad * 4) * 130 + 16 * n + r16;
        sp[0] = c[0]; sp[130] = c[1]; sp[260] = c[2]; sp[390] = c[3];
      }
    }
    __syncthreads();
    // res += relu(S + bias); LN -> Xn
    {
#pragma unroll
      for (int i = 0; i < 32; i++)
        res[i] += fmaxf(S[(obase + i) * 130 + l] + pw_b[layer * 128 + obase + i], 0.f);
      float mu, inv;
      ln_stats(res, red, t, mu, inv);
      const float* wg = norms_w + layer * 16384;
      const float* bg = norms_b + layer * 16384;
#pragma unroll
      for (int i = 0; i < 32; i++) {
        int o = obase + i;
        Xn[o * 136 + l] = f2bf((res[i] - mu) * inv * wg[o * 128 + l] + bg[o * 128 + l]);
      }
      __syncthreads();
    }
  }

  // ================= MHA (seq = channels, DK=32 per head) =================
#pragma unroll 1
  for (int h = 0; h < 4; h++) {
    __syncthreads();  // prior head's Pn/VTh readers done before overwriting S-union
    // ---- Q,K,V for this head: D[c][j'] = sum_l Xn[c][l] * W[j][l]
    {
      const unsigned short* xp = Xn + (m0 + r16) * 136 + quad * 8;
      bf16x8 x0 = *(const bf16x8*)(xp);
      bf16x8 x1 = *(const bf16x8*)(xp + 32);
      bf16x8 x2 = *(const bf16x8*)(xp + 64);
      bf16x8 x3 = *(const bf16x8*)(xp + 96);
#pragma unroll
      for (int n = 0; n < 2; n++) {
        const int jrow = 32 * h + 16 * n + r16;
        // Q (scale folded)
        {
          const unsigned short* wp = wsu + WSU_WQ + jrow * 128 + quad * 8;
          f32x4 c = {0.f, 0.f, 0.f, 0.f};
          c = mfma16(x0, *(const bf16x8*)(wp), c);
          c = mfma16(x1, *(const bf16x8*)(wp + 32), c);
          c = mfma16(x2, *(const bf16x8*)(wp + 64), c);
          c = mfma16(x3, *(const bf16x8*)(wp + 96), c);
          float bb = bq[jrow];
#pragma unroll
          for (int r = 0; r < 4; r++)
            Qh[(m0 + quad * 4 + r) * 40 + 16 * n + r16] =
                f2bf((c[r] + bb) * 0.17677669529663687f);
        }
        // K
        {
          const unsigned short* wp = wsu + WSU_WK + jrow * 128 + quad * 8;
          f32x4 c = {0.f, 0.f, 0.f, 0.f};
          c = mfma16(x0, *(const bf16x8*)(wp), c);
          c = mfma16(x1, *(const bf16x8*)(wp + 32), c);
          c = mfma16(x2, *(const bf16x8*)(wp + 64), c);
          c = mfma16(x3, *(const bf16x8*)(wp + 96), c);
          float bb = bk[jrow];
#pragma unroll
          for (int r = 0; r < 4; r++)
            Kh[(m0 + quad * 4 + r) * 40 + 16 * n + r16] = f2bf(c[r] + bb);
        }
        // V -> VTh[j'][ck] (transposed, packed pairs)
        {
          const unsigned short* wp = wsu + WSU_WV + jrow * 128 + quad * 8;
          f32x4 c = {0.f, 0.f, 0.f, 0.f};
          c = mfma16(x0, *(const bf16x8*)(wp), c);
          c = mfma16(x1, *(const bf16x8*)(wp + 32), c);
          c = mfma16(x2, *(const bf16x8*)(wp + 64), c);
          c = mfma16(x3, *(const bf16x8*)(wp + 96), c);
          float bb = bv[jrow];
          unsigned int lo = (unsigned int)f2bf(c[0] + bb) | ((unsigned int)f2bf(c[1] + bb) << 16);
          unsigned int hi = (unsigned int)f2bf(c[2] + bb) | ((unsigned int)f2bf(c[3] + bb) << 16);
          unsigned short* vp = VTh + (16 * n + r16) * 136 + m0 + quad * 4;
          *(unsigned int*)(vp) = lo;
          *(unsigned int*)(vp + 2) = hi;
        }
      }
    }
    __syncthreads();
    // ---- scores + in-register masked softmax -> Pn (unnormalized bf16)
    float linv[4];
    {
      bf16x8 aq = *(const bf16x8*)(Qh + (m0 + r16) * 40 + quad * 8);
      f32x4 sc[8];
#pragma unroll
      for (int n = 0; n < 8; n++) {
        f32x4 z = {0.f, 0.f, 0.f, 0.f};
        sc[n] = mfma16(aq, *(const bf16x8*)(Kh + (16 * n + r16) * 40 + quad * 8), z);
      }
      float mv[8];
#pragma unroll
      for (int n = 0; n < 8; n++) mv[n] = mask_s[16 * n + r16];
#pragma unroll
      for (int r = 0; r < 4; r++) {
        float sv[8];
#pragma unroll
        for (int n = 0; n < 8; n++) sv[n] = (mv[n] > 0.5f) ? NEGF : sc[n][r];
        float mx = sv[0];
#pragma unroll
        for (int n = 1; n < 8; n++) mx = fmaxf(mx, sv[n]);
        mx = fmaxf(mx, __shfl_xor(mx, 1, 64));
        mx = fmaxf(mx, __shfl_xor(mx, 2, 64));
        mx = fmaxf(mx, __shfl_xor(mx, 4, 64));
        mx = fmaxf(mx, __shfl_xor(mx, 8, 64));
        float sum = 0.f;
#pragma unroll
        for (int n = 0; n < 8; n++) { float p = __expf(sv[n] - mx); sv[n] = p; sum += p; }
        sum += __shfl_xor(sum, 1, 64);
        sum += __shfl_xor(sum, 2, 64);
        sum += __shfl_xor(sum, 4, 64);
        sum += __shfl_xor(sum, 8, 64);
        linv[r] = 1.0f / sum;
        unsigned short* pp = Pn + (m0 + quad * 4 + r) * 136 + r16;
#pragma unroll
        for (int n = 0; n < 8; n++) pp[16 * n] = f2bf(sv[n]);
      }
    }
    // ---- PV: D[cq][j'] = sum_ck P[cq][ck] * VTh[j'][ck]; *linv; -> ATT(HT)
    {
      const unsigned short* pq = Pn + (m0 + r16) * 136 + quad * 8;
      bf16x8 p0 = *(const bf16x8*)(pq);
      bf16x8 p1 = *(const bf16x8*)(pq + 32);
      bf16x8 p2 = *(const bf16x8*)(pq + 64);
      bf16x8 p3 = *(const bf16x8*)(pq + 96);
#pragma unroll
      for (int n = 0; n < 2; n++) {
        const unsigned short* vb = VTh + (16 * n + r16) * 136 + quad * 8;
        f32x4 c = {0.f, 0.f, 0.f, 0.f};
        c = mfma16(p0, *(const bf16x8*)(vb), c);
        c = mfma16(p1, *(const bf16x8*)(vb + 32), c);
        c = mfma16(p2, *(const bf16x8*)(vb + 64), c);
        c = mfma16(p3, *(const bf16x8*)(vb + 96), c);
#pragma unroll
        for (int r = 0; r < 4; r++)
          HT[(m0 + quad * 4 + r) * 136 + 32 * h + 16 * n + r16] = f2bf(c[r] * linv[r]);
      }
    }
  }
  __syncthreads();  // all PV reads of S-union done before Wo writes S

  // ---- Wo: D[c][f] = sum_j ATT[c][j] * Wo[f][j] -> S
  {
    const unsigned short* ap = HT + (m0 + r16) * 136 + quad * 8;
    bf16x8 a0 = *(const bf16x8*)(ap);
    bf16x8 a1 = *(const bf16x8*)(ap + 32);
    bf16x8 a2 = *(const bf16x8*)(ap + 64);
    bf16x8 a3 = *(const bf16x8*)(ap + 96);
#pragma unroll
    for (int n = 0; n < 8; n++) {
      const unsigned short* wp = wsu + WSU_WO + (16 * n + r16) * 128 + quad * 8;
      f32x4 c = {0.f, 0.f, 0.f, 0.f};
      c = mfma16(a0, *(const bf16x8*)(wp), c);
      c = mfma16(a1, *(const bf16x8*)(wp + 32), c);
      c = mfma16(a2, *(const bf16x8*)(wp + 64), c);
      c = mfma16(a3, *(const bf16x8*)(wp + 96), c);
      float* sp = S + (m0 + quad * 4) * 130 + 16 * n + r16;
      sp[0] = c[0]; sp[130] = c[1]; sp[260] = c[2]; sp[390] = c[3];
    }
  }
  __syncthreads();
  // res += att + bo; final LN -> X^T into HT
  {
    float bol = bo[l];
#pragma unroll
    for (int i = 0; i < 32; i++) res[i] += S[(obase + i) * 130 + l] + bol;
    float mu, inv;
    ln_stats(res, red, t, mu, inv);
#pragma unroll
    for (int i = 0; i < 32; i += 2) {
      int o = obase + i;
      float v0 = (res[i] - mu) * inv * norme_w[o * 128 + l] + norme_b[o * 128 + l];
      float v1 = (res[i + 1] - mu) * inv * norme_w[(o + 1) * 128 + l] + norme_b[(o + 1) * 128 + l];
      *(unsigned int*)(HT + l * 136 + o) =
          (unsigned int)f2bf(v0) | ((unsigned int)f2bf(v1) << 16);
    }
    __syncthreads();
  }
  // ---- FC: D[o][l] = sum_c fc[o][c] * XT[l][c] -> S
  {
    const unsigned short* fp = wsu + WSU_FC + (m0 + r16) * 128 + quad * 8;
    bf16x8 a0 = *(const bf16x8*)(fp);
    bf16x8 a1 = *(const bf16x8*)(fp + 32);
    bf16x8 a2 = *(const bf16x8*)(fp + 64);
    bf16x8 a3 = *(const bf16x8*)(fp + 96);
#pragma unroll
    for (int n = 0; n < 8; n++) {
      const unsigned short* hb = HT + (16 * n + r16) * 136 + quad * 8;
      f32x4 c = {0.f, 0.f, 0.f, 0.f};
      c = mfma16(a0, *(const bf16x8*)(hb), c);
      c = mfma16(a1, *(const bf16x8*)(hb + 32), c);
      c = mfma16(a2, *(const bf16x8*)(hb + 64), c);
      c = mfma16(a3, *(const bf16x8*)(hb + 96), c);
      float* sp = S + (m0 + quad * 4) * 130 + 16 * n + r16;
      sp[0] = c[0]; sp[130] = c[1]; sp[260] = c[2]; sp[390] = c[3];
    }
  }
  __syncthreads();
  {
    float* outb = out + (size_t)b * 16384;
#pragma unroll
    for (int i = 0; i < 32; i++) {
      float hv = S[(obase + i) * 130 + l] + fc_b[obase + i];
      outb[(obase + i) * 128 + l] = fmaxf(hv, 0.f) + res[i];
    }
  }
}

extern "C" void kernel_launch(void* const* d_in, const int* in_sizes, int n_in,
                              void* d_out, int out_size, void* d_ws, size_t ws_size,
                              hipStream_t stream) {
  const float* x       = (const float*)d_in[0];
  const int*   mask    = (const int*)d_in[1];
  const float* dw_w    = (const float*)d_in[2];
  const float* dw_b    = (const float*)d_in[3];
  const float* pw_w    = (const float*)d_in[4];
  const float* pw_b    = (const float*)d_in[5];
  const float* normb_w = (const float*)d_in[6];
  const float* normb_b = (const float*)d_in[7];
  const float* norms_w = (const float*)d_in[8];
  const float* norms_b = (const float*)d_in[9];
  const float* norme_w = (const float*)d_in[10];
  const float* norme_b = (const float*)d_in[11];
  const float* Wq      = (const float*)d_in[12];
  const float* bq      = (const float*)d_in[13];
  const float* Wk      = (const float*)d_in[14];
  const float* bk      = (const float*)d_in[15];
  const float* Wv      = (const float*)d_in[16];
  const float* bv      = (const float*)d_in[17];
  const float* Wo      = (const float*)d_in[18];
  const float* bo      = (const float*)d_in[19];
  const float* fc_w    = (const float*)d_in[20];
  const float* fc_b    = (const float*)d_in[21];
  float* out = (float*)d_out;
  unsigned short* wsu = (unsigned short*)d_ws;
  const float* pe = (const float*)(wsu + WSU_END);
  int B = in_sizes[0] / 16384;

  prep_kernel<<<dim3(10, 128), dim3(128), 0, stream>>>(pw_w, fc_w, Wo, Wq, Wk, Wv, wsu);
  enc_kernel<<<dim3(B), dim3(512), 0, stream>>>(
      x, mask, dw_w, dw_b, pw_b, normb_w, normb_b, norms_w, norms_b,
      norme_w, norme_b, bq, bk, bv, bo, fc_b, wsu, pe, out);
}